// Round 6
// baseline (602.230 us; speedup 1.0000x reference)
//
#include <hip/hip_runtime.h>

#define NN 256
#define BIGF 1e8f
#define GAMF 0.01f
#define INVG 100.0f

__global__ void zero_out_k(float* out) {
    if (threadIdx.x == 0) out[0] = 0.0f;
}

// One wave per batch. Lane t owns rows i = 4t+1 .. 4t+4. No __syncthreads in
// the DP loops: cross-lane row-boundary values travel by shuffle.
__global__ __launch_bounds__(64)
void dilate_wave_k(const float* __restrict__ pred, const float* __restrict__ target,
                   float* __restrict__ Rws, float* __restrict__ out)
{
    __shared__ float sP[NN];
    const int t = threadIdx.x;
    const int b = blockIdx.x;
    const size_t base = (size_t)b * (NN * NN);
    const int r0 = 4 * t;                 // rows are r0+1 .. r0+4

    // pred row -> LDS (read via rolling register window in the loops)
    #pragma unroll
    for (int k = 0; k < 4; ++k) sP[r0 + k] = pred[b * NN + r0 + k];
    __syncthreads();                      // single wave: near-free

    // target values for owned rows (registers forever)
    float tT[4];
    #pragma unroll
    for (int k = 0; k < 4; ++k) tT[k] = target[b * NN + r0 + k];
    // sT[i] for i = r0+4 (needed by backward D[i+1,*] at k=3); lane 63 value unused
    float tTx = target[b * NN + ((r0 + 4 < NN) ? (r0 + 4) : (NN - 1))];

    // ---------------- forward wavefront (no barriers) ----------------
    float rp[4], rpp[4];                  // R diag s-1, s-2 for owned rows
    #pragma unroll
    for (int k = 0; k < 4; ++k) { rp[k] = BIGF; rpp[k] = BIGF; }

    // pw[k] = sP[j-1] for cell k at step s, j = s - (r0+1+k); rolling window
    float pw[4] = {0.f, 0.f, 0.f, 0.f};
    int ip0 = 0 - r0;                     // s=2: index s-2-r0
    float pnext = (ip0 >= 0 && ip0 < NN) ? sP[ip0] : 0.0f;

    int off = 0;                          // packed offset of diag s
    for (int s = 2; s <= 2 * NN; ++s) {
        pw[3] = pw[2]; pw[2] = pw[1]; pw[1] = pw[0]; pw[0] = pnext;
        int ipn = s - 1 - r0;             // prefetch for step s+1
        pnext = (ipn >= 0 && ipn < NN) ? sP[ipn] : 0.0f;

        // boundary row r0 values from lane t-1 (its row 4 = k=3)
        float upS = __shfl_up(rp[3], 1, 64);    // R[r0, j]    (diag s-1)
        float dgS = __shfl_up(rpp[3], 1, 64);   // R[r0, j-1]  (diag s-2)
        if (t == 0) { upS = BIGF; dgS = (s == 2) ? 0.0f : BIGF; }  // row-0 border, R[0,0]=0

        const int ilo = (s - NN > 1) ? (s - NN) : 1;
        float rc[4];
        #pragma unroll
        for (int k = 0; k < 4; ++k) {
            int i = r0 + 1 + k;
            int j = s - i;
            float dg = (k == 0) ? dgS : rpp[k - 1];
            float up = (k == 0) ? upS : rp[k - 1];
            float lf = rp[k];
            float diff = tT[k] - pw[k];
            float d = diff * diff;
            float m = fminf(dg, fminf(up, lf));
            float z = __expf((m - dg) * INVG) + __expf((m - up) * INVG)
                    + __expf((m - lf) * INVG);
            float val = d + m - GAMF * __logf(z);
            bool act = (j >= 1) && (j <= NN);
            val = act ? val : BIGF;       // sentinel keeps border semantics
            if (act) Rws[base + off + (i - ilo)] = val;
            rc[k] = val;
        }
        #pragma unroll
        for (int k = 0; k < 4; ++k) { rpp[k] = rp[k]; rp[k] = rc[k]; }
        const int ihi = (s - 1 < NN) ? (s - 1) : NN;
        off += ihi - ilo + 1;
    }
    float rNN = rp[3];                    // lane 63 holds R[N,N]

    // ---------------- backward wavefront (no barriers) ----------------
    float Rp[4], Rpp[4], Ep[4], Epp[4];   // diag s+1, s+2
    #pragma unroll
    for (int k = 0; k < 4; ++k) { Rp[k] = -BIGF; Rpp[k] = -BIGF; Ep[k] = 0.f; Epp[k] = 0.f; }

    // qw[m] = sP[s-1-r0-m], m=0..4  (cell k uses sP[j]=qw[k], sP[j-1]=qw[k+1])
    float qw[5];
    #pragma unroll
    for (int m = 0; m < 5; ++m) {
        int id = 2 * NN - 1 - r0 - m;
        qw[m] = (id >= 0 && id < NN) ? sP[id] : 0.0f;
    }

    // prefetch R of diag s=2N (one full step of latency hiding thereafter)
    float rvp[4];
    int offb = NN * NN;
    {
        int s = 2 * NN;
        int ilo = (s - NN > 1) ? (s - NN) : 1;
        int ihi = (s - 1 < NN) ? (s - 1) : NN;
        offb -= ihi - ilo + 1;
        #pragma unroll
        for (int k = 0; k < 4; ++k) {
            int i = r0 + 1 + k, j = s - i;
            rvp[k] = -BIGF;
            if (j >= 1 && j <= NN) rvp[k] = Rws[base + offb + (i - ilo)];
        }
    }

    float acc = 0.0f;                     // sum E[i,j]*(i-j)^2 over owned cells
    for (int s = 2 * NN; s >= 2; --s) {
        float rv[4];
        #pragma unroll
        for (int k = 0; k < 4; ++k) rv[k] = rvp[k];   // vmcnt wait here (hidden)

        if (s > 2) {                      // issue prefetch for diag s-1
            int sm = s - 1;
            int ilo_m = (sm - NN > 1) ? (sm - NN) : 1;
            int ihi_m = (sm - 1 < NN) ? (sm - 1) : NN;
            offb -= ihi_m - ilo_m + 1;
            #pragma unroll
            for (int k = 0; k < 4; ++k) {
                int i = r0 + 1 + k, j = sm - i;
                rvp[k] = -BIGF;
                if (j >= 1 && j <= NN) rvp[k] = Rws[base + offb + (i - ilo_m)];
            }
        }

        int iq = s - 6 - r0;              // qw[4] for step s-1, issued early
        float qnext = (iq >= 0 && iq < NN) ? sP[iq] : 0.0f;

        // boundary row r0+5 values from lane t+1 (its row 1 = k=0)
        float RdS = __shfl_down(Rp[0], 1, 64);
        float RgS = __shfl_down(Rpp[0], 1, 64);
        float EdS = __shfl_down(Ep[0], 1, 64);
        float EgS = __shfl_down(Epp[0], 1, 64);
        if (t == 63) { RdS = -BIGF; RgS = -BIGF; EdS = 0.0f; EgS = 0.0f; }

        float Rc[4], Ec[4];
        #pragma unroll
        for (int k = 0; k < 4; ++k) {
            int i = r0 + 1 + k;
            int j = s - i;
            bool act = (j >= 1) && (j <= NN);
            float rvk = rv[k];
            float rdn = (k < 3) ? Rp[k + 1]  : RdS;   // R[i+1, j]
            float rrt = Rp[k];                        // R[i,   j+1]
            float rdg = (k < 3) ? Rpp[k + 1] : RgS;   // R[i+1, j+1]
            float edn = (k < 3) ? Ep[k + 1]  : EdS;
            float ert = Ep[k];
            float edg = (k < 3) ? Epp[k + 1] : EgS;
            float tE = (k < 3) ? tT[k + 1] : tTx;     // sT[i]
            float d1 = tE    - qw[k + 1]; d1 *= d1;   // D[i+1, j]
            float d2 = tT[k] - qw[k];     d2 *= d2;   // D[i,   j+1]
            float d3 = tE    - qw[k];     d3 *= d3;   // D[i+1, j+1]
            float ev = __expf((rdn - rvk - d1) * INVG) * edn
                     + __expf((rrt - rvk - d2) * INVG) * ert
                     + __expf((rdg - rvk - d3) * INVG) * edg;
            if (s == 2 * NN && k == 3 && t == 63) ev = 1.0f;  // E[N,N] seed
            if (!act) { rvk = -BIGF; ev = 0.0f; }     // sentinel (also kills any inf*0)
            float dj = (float)(i - j);
            acc += ev * dj * dj;
            Rc[k] = rvk; Ec[k] = ev;
        }
        #pragma unroll
        for (int k = 0; k < 4; ++k) { Rpp[k] = Rp[k]; Rp[k] = Rc[k]; Epp[k] = Ep[k]; Ep[k] = Ec[k]; }
        qw[0] = qw[1]; qw[1] = qw[2]; qw[2] = qw[3]; qw[3] = qw[4]; qw[4] = qnext;
    }

    // ---------------- reduce + output ----------------
    #pragma unroll
    for (int o = 32; o >= 1; o >>= 1) acc += __shfl_down(acc, o, 64);
    float rN = __shfl(rNN, 63, 64);
    if (t == 0) {
        const float SH = 0.8f / 128.0f;               // alpha / B
        const float TM = 0.2f / (128.0f * 65536.0f);  // (1-alpha) / (B*N*N)
        atomicAdd(out, SH * rN + TM * acc);
    }
}

extern "C" void kernel_launch(void* const* d_in, const int* in_sizes, int n_in,
                              void* d_out, int out_size, void* d_ws, size_t ws_size,
                              hipStream_t stream) {
    const float* pred   = (const float*)d_in[0];
    const float* target = (const float*)d_in[1];
    float* out = (float*)d_out;
    float* Rws = (float*)d_ws;   // 128*256*256*4 = 33.6 MB

    zero_out_k<<<1, 64, 0, stream>>>(out);
    dilate_wave_k<<<128, 64, 0, stream>>>(pred, target, Rws, out);
}

// Round 7
// 578.467 us; speedup vs baseline: 1.0411x; 1.0411x over previous
//
#include <hip/hip_runtime.h>

#define NN 256
#define BIGF 1e8f
#define GAMF 0.01f
#define INVG 100.0f

__global__ void zero_out_k(float* out) {
    if (threadIdx.x == 0) out[0] = 0.0f;
}

// One wave per batch. Lane t owns rows i = 4t+1 .. 4t+4. No barriers; all
// cross-lane boundary values are LOOP-CARRIED shuffles (issued one step
// before use, so ds_bpermute latency is off the critical path).
__global__ __launch_bounds__(64)
void dilate_wave_k(const float* __restrict__ pred, const float* __restrict__ target,
                   float* __restrict__ Rws, float* __restrict__ out)
{
    __shared__ float sP[NN];
    const int t = threadIdx.x;
    const int b = blockIdx.x;
    const size_t base = (size_t)b * (NN * NN);
    const int r0 = 4 * t;                 // rows are r0+1 .. r0+4

    #pragma unroll
    for (int k = 0; k < 4; ++k) sP[r0 + k] = pred[b * NN + r0 + k];
    __syncthreads();                      // single wave: near-free

    float tT[4];
    #pragma unroll
    for (int k = 0; k < 4; ++k) tT[k] = target[b * NN + r0 + k];
    float tTx = target[b * NN + ((r0 + 4 < NN) ? (r0 + 4) : (NN - 1))];

    // ---------------- forward wavefront ----------------
    float rp[4], rpp[4];
    #pragma unroll
    for (int k = 0; k < 4; ++k) { rp[k] = BIGF; rpp[k] = BIGF; }

    float pw[4] = {0.f, 0.f, 0.f, 0.f};
    int ip0 = 0 - r0;
    float pnext = (ip0 >= 0 && ip0 < NN) ? sP[ip0] : 0.0f;

    // loop-carried boundary values from lane t-1:
    // upS = neighbor rp[3] (diag s-1), dgS = neighbor rpp[3] (diag s-2)
    float upS = BIGF, dgS = BIGF;

    int off = 0;
    for (int s = 2; s <= 2 * NN; ++s) {
        pw[3] = pw[2]; pw[2] = pw[1]; pw[1] = pw[0]; pw[0] = pnext;
        int ipn = s - 1 - r0;
        pnext = (ipn >= 0 && ipn < NN) ? sP[ipn] : 0.0f;

        float up0 = upS, dg0 = dgS;
        if (t == 0) { up0 = BIGF; dg0 = (s == 2) ? 0.0f : BIGF; }  // border, R[0,0]=0

        const int ilo = (s - NN > 1) ? (s - NN) : 1;
        float rc[4];
        #pragma unroll
        for (int k = 0; k < 4; ++k) {
            int i = r0 + 1 + k;
            int j = s - i;
            float dg = (k == 0) ? dg0 : rpp[k - 1];
            float up = (k == 0) ? up0 : rp[k - 1];
            float lf = rp[k];
            float diff = tT[k] - pw[k];
            float d = diff * diff;
            float m = fminf(dg, fminf(up, lf));
            float z = __expf((m - dg) * INVG) + __expf((m - up) * INVG)
                    + __expf((m - lf) * INVG);
            float val = d + m - GAMF * __logf(z);
            bool act = (j >= 1) && (j <= NN);
            val = act ? val : BIGF;
            if (act) Rws[base + off + (i - ilo)] = val;
            rc[k] = val;
        }
        // issue next step's boundary shuffle NOW (consumed next iteration)
        float nUp = __shfl_up(rc[3], 1, 64);
        #pragma unroll
        for (int k = 0; k < 4; ++k) { rpp[k] = rp[k]; rp[k] = rc[k]; }
        dgS = upS;       // neighbor diag s-1 becomes next step's s-2... (rotated)
        upS = nUp;       // neighbor diag s for next step
        const int ihi = (s - 1 < NN) ? (s - 1) : NN;
        off += ihi - ilo + 1;
    }
    float rNN = rp[3];                    // lane 63 holds R[N,N]

    // ---------------- backward wavefront ----------------
    float Rp[4], Rpp[4], Ep[4], Epp[4];
    #pragma unroll
    for (int k = 0; k < 4; ++k) { Rp[k] = -BIGF; Rpp[k] = -BIGF; Ep[k] = 0.f; Epp[k] = 0.f; }

    float qw[5];
    #pragma unroll
    for (int m = 0; m < 5; ++m) {
        int id = 2 * NN - 1 - r0 - m;
        qw[m] = (id >= 0 && id < NN) ? sP[id] : 0.0f;
    }

    float rvp[4];
    int offb = NN * NN;
    {
        int s = 2 * NN;
        int ilo = (s - NN > 1) ? (s - NN) : 1;
        int ihi = (s - 1 < NN) ? (s - 1) : NN;
        offb -= ihi - ilo + 1;
        #pragma unroll
        for (int k = 0; k < 4; ++k) {
            int i = r0 + 1 + k, j = s - i;
            rvp[k] = -BIGF;
            if (j >= 1 && j <= NN) rvp[k] = Rws[base + offb + (i - ilo)];
        }
    }

    // loop-carried boundary values from lane t+1:
    // RdS/EdS = neighbor Rp[0]/Ep[0] (diag s+1); RgS/EgS = neighbor Rpp[0]/Epp[0] (s+2)
    float RdS = -BIGF, RgS = -BIGF, EdS = 0.0f, EgS = 0.0f;

    float ac0 = 0.f, ac1 = 0.f, ac2 = 0.f, ac3 = 0.f;
    for (int s = 2 * NN; s >= 2; --s) {
        float rv[4];
        #pragma unroll
        for (int k = 0; k < 4; ++k) rv[k] = rvp[k];   // waits on loads issued last step

        if (s > 2) {                      // prefetch diag s-1
            int sm = s - 1;
            int ilo_m = (sm - NN > 1) ? (sm - NN) : 1;
            int ihi_m = (sm - 1 < NN) ? (sm - 1) : NN;
            offb -= ihi_m - ilo_m + 1;
            #pragma unroll
            for (int k = 0; k < 4; ++k) {
                int i = r0 + 1 + k, j = sm - i;
                rvp[k] = -BIGF;
                if (j >= 1 && j <= NN) rvp[k] = Rws[base + offb + (i - ilo_m)];
            }
        }

        int iq = s - 6 - r0;
        float qnext = (iq >= 0 && iq < NN) ? sP[iq] : 0.0f;

        float Rd = RdS, Rg = RgS, Ed = EdS, Eg = EgS;
        if (t == 63) { Rd = -BIGF; Rg = -BIGF; Ed = 0.0f; Eg = 0.0f; }

        float Rc[4], Ec[4];
        #pragma unroll
        for (int k = 0; k < 4; ++k) {
            int i = r0 + 1 + k;
            int j = s - i;
            bool act = (j >= 1) && (j <= NN);
            float rvk = rv[k];
            float rdn = (k < 3) ? Rp[k + 1]  : Rd;    // R[i+1, j]
            float rrt = Rp[k];                        // R[i,   j+1]
            float rdg = (k < 3) ? Rpp[k + 1] : Rg;    // R[i+1, j+1]
            float edn = (k < 3) ? Ep[k + 1]  : Ed;
            float ert = Ep[k];
            float edg = (k < 3) ? Epp[k + 1] : Eg;
            float tE = (k < 3) ? tT[k + 1] : tTx;     // sT[i]
            float d1 = tE    - qw[k + 1]; d1 *= d1;   // D[i+1, j]
            float d2 = tT[k] - qw[k];     d2 *= d2;   // D[i,   j+1]
            float d3 = tE    - qw[k];     d3 *= d3;   // D[i+1, j+1]
            float ev = __expf((rdn - rvk - d1) * INVG) * edn
                     + __expf((rrt - rvk - d2) * INVG) * ert
                     + __expf((rdg - rvk - d3) * INVG) * edg;
            if (s == 2 * NN && k == 3 && t == 63) ev = 1.0f;  // E[N,N] seed
            if (!act) { rvk = -BIGF; ev = 0.0f; }
            float dj = (float)(i - j);
            float w = ev * dj * dj;
            if (k == 0) ac0 += w; else if (k == 1) ac1 += w;
            else if (k == 2) ac2 += w; else ac3 += w;
            Rc[k] = rvk; Ec[k] = ev;
        }
        // issue next step's boundary shuffles NOW (consumed next iteration)
        float nRd = __shfl_down(Rc[0], 1, 64);
        float nEd = __shfl_down(Ec[0], 1, 64);
        #pragma unroll
        for (int k = 0; k < 4; ++k) { Rpp[k] = Rp[k]; Rp[k] = Rc[k]; Epp[k] = Ep[k]; Ep[k] = Ec[k]; }
        RgS = RdS; RdS = nRd;
        EgS = EdS; EdS = nEd;
        qw[0] = qw[1]; qw[1] = qw[2]; qw[2] = qw[3]; qw[3] = qw[4]; qw[4] = qnext;
    }

    // ---------------- reduce + output ----------------
    float acc = (ac0 + ac1) + (ac2 + ac3);
    #pragma unroll
    for (int o = 32; o >= 1; o >>= 1) acc += __shfl_down(acc, o, 64);
    float rN = __shfl(rNN, 63, 64);
    if (t == 0) {
        const float SH = 0.8f / 128.0f;               // alpha / B
        const float TM = 0.2f / (128.0f * 65536.0f);  // (1-alpha) / (B*N*N)
        atomicAdd(out, SH * rN + TM * acc);
    }
}

extern "C" void kernel_launch(void* const* d_in, const int* in_sizes, int n_in,
                              void* d_out, int out_size, void* d_ws, size_t ws_size,
                              hipStream_t stream) {
    const float* pred   = (const float*)d_in[0];
    const float* target = (const float*)d_in[1];
    float* out = (float*)d_out;
    float* Rws = (float*)d_ws;   // 128*256*256*4 = 33.6 MB

    zero_out_k<<<1, 64, 0, stream>>>(out);
    dilate_wave_k<<<128, 64, 0, stream>>>(pred, target, Rws, out);
}

// Round 10
// 522.706 us; speedup vs baseline: 1.1521x; 1.1067x over previous
//
#include <hip/hip_runtime.h>

#define NN 256
#define BIGF 1e8f
#define GAMF 0.01f
#define INVG 100.0f

__global__ void zero_out_k(float* out) {
    if (threadIdx.x == 0) out[0] = 0.0f;
}

// One wave per batch. Lane t owns rows i = 4t+1 .. 4t+4. No barriers.
// Cross-lane boundary values are loop-carried shuffles whose SOURCE cell is
// computed first within each step (max slack). Backward R reads are
// software-pipelined 4 diagonals deep (static buffers, unrolled x4).
__global__ __launch_bounds__(64)
void dilate_wave_k(const float* __restrict__ pred, const float* __restrict__ target,
                   float* __restrict__ Rws, float* __restrict__ out)
{
    __shared__ float sP[NN];
    const int t = threadIdx.x;
    const int b = blockIdx.x;
    const size_t base = (size_t)b * (NN * NN);
    const int r0 = 4 * t;                 // rows r0+1 .. r0+4

    #pragma unroll
    for (int k = 0; k < 4; ++k) sP[r0 + k] = pred[b * NN + r0 + k];
    __syncthreads();

    float tT[4];
    #pragma unroll
    for (int k = 0; k < 4; ++k) tT[k] = target[b * NN + r0 + k];
    float tTx = target[b * NN + ((r0 + 4 < NN) ? (r0 + 4) : (NN - 1))];

    // ---------------- forward wavefront ----------------
    float rp[4], rpp[4];
    #pragma unroll
    for (int k = 0; k < 4; ++k) { rp[k] = BIGF; rpp[k] = BIGF; }

    float pw[4] = {0.f, 0.f, 0.f, 0.f};
    int ip0 = 0 - r0;
    float pnext = (ip0 >= 0 && ip0 < NN) ? sP[ip0] : 0.0f;

    float upS = BIGF, dgS = BIGF;         // loop-carried boundary (lane t-1)
    int off = 0;

#define FCELL(kk, dgv, upv) { \
    int i_ = r0 + 1 + (kk); int j_ = s - i_; \
    float dg_ = (dgv), up_ = (upv), lf_ = rp[kk]; \
    float diff_ = tT[kk] - pw[kk]; float d_ = diff_ * diff_; \
    float m_ = fminf(dg_, fminf(up_, lf_)); \
    float z_ = __expf((m_ - dg_) * INVG) + __expf((m_ - up_) * INVG) \
             + __expf((m_ - lf_) * INVG); \
    float val_ = d_ + m_ - GAMF * __logf(z_); \
    bool act_ = (j_ >= 1) && (j_ <= NN); \
    val_ = act_ ? val_ : BIGF; \
    if (act_) Rws[base + off + (i_ - ilo)] = val_; \
    rc[kk] = val_; }

    #pragma unroll 2
    for (int s = 2; s <= 2 * NN; ++s) {
        pw[3] = pw[2]; pw[2] = pw[1]; pw[1] = pw[0]; pw[0] = pnext;
        int ipn = s - 1 - r0;
        pnext = (ipn >= 0 && ipn < NN) ? sP[ipn] : 0.0f;

        float up0 = upS, dg0 = dgS;
        if (t == 0) { up0 = BIGF; dg0 = (s == 2) ? 0.0f : BIGF; }

        const int ilo = (s - NN > 1) ? (s - NN) : 1;
        float rc[4];
        FCELL(3, rpp[2], rp[2])                   // shuffle source first
        float nUp = __shfl_up(rc[3], 1, 64);      // issued early, used next step
        FCELL(0, dg0, up0)
        FCELL(1, rpp[0], rp[0])
        FCELL(2, rpp[1], rp[1])

        #pragma unroll
        for (int k = 0; k < 4; ++k) { rpp[k] = rp[k]; rp[k] = rc[k]; }
        dgS = upS; upS = nUp;
        const int ihi = (s - 1 < NN) ? (s - 1) : NN;
        off += ihi - ilo + 1;
    }
    float rNN = rp[3];                    // lane 63 holds R[N,N]

    // ---------------- backward wavefront ----------------
    float Rp[4], Rpp[4], Ep[4], Epp[4];
    #pragma unroll
    for (int k = 0; k < 4; ++k) { Rp[k] = -BIGF; Rpp[k] = -BIGF; Ep[k] = 0.f; Epp[k] = 0.f; }

    float qw[5];
    #pragma unroll
    for (int m = 0; m < 5; ++m) {
        int id = 2 * NN - 1 - r0 - m;
        qw[m] = (id >= 0 && id < NN) ? sP[id] : 0.0f;
    }

    float RdS = -BIGF, RgS = -BIGF, EdS = 0.0f, EgS = 0.0f;
    float ac0 = 0.f, ac1 = 0.f, ac2 = 0.f, ac3 = 0.f;
    int offb = NN * NN;
    float bA[4], bB[4], bC[4], bD[4];

#define ISSUE(ss, bname) do { if ((ss) >= 2) { \
    int ilo_ = ((ss) - NN > 1) ? ((ss) - NN) : 1; \
    int ihi_ = ((ss) - 1 < NN) ? ((ss) - 1) : NN; \
    offb -= ihi_ - ilo_ + 1; \
    for (int k = 0; k < 4; ++k) { \
        int i_ = r0 + 1 + k, j_ = (ss) - i_; \
        bname[k] = (j_ >= 1 && j_ <= NN) ? Rws[base + offb + (i_ - ilo_)] : -BIGF; \
    } } } while (0)

#define BCELL(kk, bname, rdnv, rdgv, ednv, edgv) { \
    int i_ = r0 + 1 + (kk); int j_ = s_ - i_; \
    bool act_ = (j_ >= 1) && (j_ <= NN); \
    float rvk_ = bname[kk]; \
    float rdn_ = (rdnv), rrt_ = Rp[kk], rdg_ = (rdgv); \
    float edn_ = (ednv), ert_ = Ep[kk], edg_ = (edgv); \
    float tE_ = ((kk) < 3) ? tT[(kk) + 1 > 3 ? 3 : (kk) + 1] : tTx; \
    float d1_ = tE_ - qw[(kk) + 1]; d1_ *= d1_; \
    float d2_ = tT[kk] - qw[kk];    d2_ *= d2_; \
    float d3_ = tE_ - qw[kk];       d3_ *= d3_; \
    float ev_ = __expf((rdn_ - rvk_ - d1_) * INVG) * edn_ \
              + __expf((rrt_ - rvk_ - d2_) * INVG) * ert_ \
              + __expf((rdg_ - rvk_ - d3_) * INVG) * edg_; \
    if (s_ == 2 * NN && (kk) == 3 && t == 63) ev_ = 1.0f; \
    if (!act_) { rvk_ = -BIGF; ev_ = 0.f; } \
    float dj_ = (float)(i_ - j_); float w_ = ev_ * dj_ * dj_; \
    if ((kk) == 0) ac0 += w_; else if ((kk) == 1) ac1 += w_; \
    else if ((kk) == 2) ac2 += w_; else ac3 += w_; \
    Rc_[kk] = rvk_; Ec_[kk] = ev_; }

#define STEP(ss, bname) do { \
    const int s_ = (ss); \
    int iq_ = s_ - 6 - r0; \
    float qn_ = (iq_ >= 0 && iq_ < NN) ? sP[iq_] : 0.0f; \
    float Rd_ = RdS, Rg_ = RgS, Ed_ = EdS, Eg_ = EgS; \
    if (t == 63) { Rd_ = -BIGF; Rg_ = -BIGF; Ed_ = 0.f; Eg_ = 0.f; } \
    float Rc_[4], Ec_[4]; \
    BCELL(0, bname, Rp[1], Rpp[1], Ep[1], Epp[1])     /* shuffle source first */ \
    float nRd_ = __shfl_down(Rc_[0], 1, 64); \
    float nEd_ = __shfl_down(Ec_[0], 1, 64); \
    BCELL(1, bname, Rp[2], Rpp[2], Ep[2], Epp[2]) \
    BCELL(2, bname, Rp[3], Rpp[3], Ep[3], Epp[3]) \
    BCELL(3, bname, Rd_,   Rg_,    Ed_,   Eg_) \
    for (int k = 0; k < 4; ++k) { Rpp[k] = Rp[k]; Rp[k] = Rc_[k]; \
                                  Epp[k] = Ep[k]; Ep[k] = Ec_[k]; } \
    RgS = RdS; RdS = nRd_; EgS = EdS; EdS = nEd_; \
    qw[0] = qw[1]; qw[1] = qw[2]; qw[2] = qw[3]; qw[3] = qw[4]; qw[4] = qn_; \
} while (0)

    // prologue: 4 diagonals in flight
    ISSUE(2 * NN,     bA);
    ISSUE(2 * NN - 1, bB);
    ISSUE(2 * NN - 2, bC);
    ISSUE(2 * NN - 3, bD);

    for (int sb = 2 * NN; sb >= 8; sb -= 4) {
        STEP(sb,     bA); ISSUE(sb - 4, bA);
        STEP(sb - 1, bB); ISSUE(sb - 5, bB);
        STEP(sb - 2, bC); ISSUE(sb - 6, bC);
        STEP(sb - 3, bD); ISSUE(sb - 7, bD);
    }
    STEP(4, bA);
    STEP(3, bB);
    STEP(2, bC);

    // ---------------- reduce + output ----------------
    float acc = (ac0 + ac1) + (ac2 + ac3);
    #pragma unroll
    for (int o = 32; o >= 1; o >>= 1) acc += __shfl_down(acc, o, 64);
    float rN = __shfl(rNN, 63, 64);
    if (t == 0) {
        const float SH = 0.8f / 128.0f;               // alpha / B
        const float TM = 0.2f / (128.0f * 65536.0f);  // (1-alpha) / (B*N*N)
        atomicAdd(out, SH * rN + TM * acc);
    }
}

extern "C" void kernel_launch(void* const* d_in, const int* in_sizes, int n_in,
                              void* d_out, int out_size, void* d_ws, size_t ws_size,
                              hipStream_t stream) {
    const float* pred   = (const float*)d_in[0];
    const float* target = (const float*)d_in[1];
    float* out = (float*)d_out;
    float* Rws = (float*)d_ws;   // 128*256*256*4 = 33.6 MB

    zero_out_k<<<1, 64, 0, stream>>>(out);
    dilate_wave_k<<<128, 64, 0, stream>>>(pred, target, Rws, out);
}